// Round 9
// baseline (561.796 us; speedup 1.0000x reference)
//
#include <hip/hip_runtime.h>
#include <hip/hip_bf16.h>

typedef __attribute__((ext_vector_type(8))) short bf16x8;
typedef __attribute__((ext_vector_type(4))) float f32x4;

static __device__ __forceinline__ void stf(float* p, size_t i, float v) { p[i] = v; }
static __device__ __forceinline__ void stf(__hip_bfloat16* p, size_t i, float v) { p[i] = __float2bfloat16(v); }

static __device__ __forceinline__ void gload_lds16(const void* g, void* l) {
  __builtin_amdgcn_global_load_lds((const __attribute__((address_space(1))) void*)g,
                                   (__attribute__((address_space(3))) void*)l, 16, 0, 0);
}

// ---------- weight transpose + bf16 convert: W[K][N] f32 -> WT[N][K] bf16 ----------
__global__ void wt_kernel(const float* __restrict__ W, __hip_bfloat16* __restrict__ WT, int K, int N) {
  __shared__ float tile[32][33];
  const int kb = blockIdx.y * 32, nb = blockIdx.x * 32;
  const int tx = threadIdx.x & 31, ty = threadIdx.x >> 5;
#pragma unroll
  for (int i = 0; i < 4; ++i)
    tile[ty + i * 8][tx] = W[(size_t)(kb + ty + i * 8) * N + nb + tx];
  __syncthreads();
#pragma unroll
  for (int i = 0; i < 4; ++i)
    WT[(size_t)(nb + ty + i * 8) * K + kb + tx] = __float2bfloat16(tile[tx][ty + i * 8]);
}

// ---------- conv prep: wT[tap][c] = w[c*9+tap]; s[c]=rsqrt(var+eps)*g; t[c]=b-mean*s ----------
__global__ void convprep_kernel(const float* __restrict__ w, const float* __restrict__ bng,
                                const float* __restrict__ bnb, const float* __restrict__ bnm,
                                const float* __restrict__ bnv, float* __restrict__ wT,
                                float* __restrict__ st) {
  const int i = blockIdx.x * 256 + threadIdx.x;
  if (i < 576 * 9) {
    const int t = i / 576, c = i - t * 576;
    wT[i] = w[c * 9 + t];
  }
  if (i < 576) {
    const float s = rsqrtf(bnv[i] + 1e-5f) * bng[i];
    st[i] = s;
    st[576 + i] = bnb[i] - bnm[i] * s;
  }
}

// ---------- fused LN -> bf16: one wave per 576-elem row ----------
__global__ void ln_bf16_kernel(const float* __restrict__ x, const float* __restrict__ g,
                               const float* __restrict__ b, __hip_bfloat16* __restrict__ y) {
  const int row = blockIdx.x * 4 + (threadIdx.x >> 6);
  const int lane = threadIdx.x & 63;
  const float* p = x + (size_t)row * 576;
  float vals[9];
  float s = 0.f, ss = 0.f;
#pragma unroll
  for (int i = 0; i < 9; ++i) {
    float v = p[lane + i * 64];
    vals[i] = v; s += v; ss += v * v;
  }
#pragma unroll
  for (int o = 32; o; o >>= 1) { s += __shfl_down(s, o); ss += __shfl_down(ss, o); }
  s = __shfl(s, 0); ss = __shfl(ss, 0);
  const float m = s * (1.f / 576.f);
  const float rstd = rsqrtf(ss * (1.f / 576.f) - m * m + 1e-5f);
  __hip_bfloat16* q = y + (size_t)row * 576;
#pragma unroll
  for (int i = 0; i < 9; ++i) {
    const int c = lane + i * 64;
    q[c] = __float2bfloat16((vals[i] - m) * rstd * g[c] + b[c]);
  }
}

// ---------- MFMA GEMM: C[M,N] = epi(A[M,K] @ BT[N,K]^T + bias) ----------
// 256x192 tile, BK=64, 8 waves (2Mx4N, wave tile 128x48), dbuf LDS 114.7KB,
// counted-vmcnt 2-deep prefetch ring (T3+T4): stage(t+2) after post-compute
// barrier; pre-compute wait = vmcnt(7) (7 gload_lds per tile per thread),
// never drained to 0 in steady state. Raw s_barrier + sched_barrier fences.
// EPI: 0 none, 1 +res, 2 exact GELU
template <int EPI, typename TO>
__global__ __launch_bounds__(512, 1) void gemm_bt(
    const __hip_bfloat16* __restrict__ A, const __hip_bfloat16* __restrict__ BT,
    const float* __restrict__ bias, const float* __restrict__ res, TO* __restrict__ C,
    int M, int N, int K) {
  constexpr int BM = 256, BN = 192;
  constexpr int WM = 128, WN = 48;          // wave tile
  constexpr int MI = 8, NI = 3;             // 16x16 frags per wave
  constexpr int AI = 4, BI = 3;             // stage iterations (512 thr, 16B)
  __shared__ __hip_bfloat16 sA[2][BM * 64];
  __shared__ __hip_bfloat16 sB[2][BN * 64];
  const int t = threadIdx.x;
  const int lane = t & 63;
  const int w = t >> 6;
  // bijective XCD swizzle (m204), panel-major 1D grid
  const int nwg = gridDim.x;
  const int qq = nwg >> 3, r = nwg & 7;
  const int xcd = blockIdx.x & 7, lidx = blockIdx.x >> 3;
  const int wgid = (xcd < r ? xcd * (qq + 1) : r * (qq + 1) + (xcd - r) * qq) + lidx;
  const int nx = N / BN;
  const int bm = (wgid / nx) * BM, bn = (wgid % nx) * BN;
  const int wm = (w >> 2) * WM, wn = (w & 3) * WN;
  const int l15 = lane & 15, l4 = lane >> 4;

  f32x4 acc[MI][NI];
#pragma unroll
  for (int mi = 0; mi < MI; ++mi)
#pragma unroll
    for (int ni = 0; ni < NI; ++ni) acc[mi][ni] = (f32x4){0.f, 0.f, 0.f, 0.f};

  const int wave_base = t & ~63;

  auto stage = [&](int buf, int kt) {
    const int k0 = kt << 6;
#pragma unroll
    for (int i = 0; i < AI; ++i) {
      const int slot = i * 512 + t;
      const int row = slot >> 3, kst = slot & 7;
      const int ksrc = kst ^ (row & 7);
      const __hip_bfloat16* g = A + (size_t)(bm + row) * K + k0 + ksrc * 8;
      gload_lds16(g, sA[buf] + (i * 512 + wave_base) * 8);
    }
#pragma unroll
    for (int i = 0; i < BI; ++i) {
      const int slot = i * 512 + t;
      const int row = slot >> 3, kst = slot & 7;
      const int ksrc = kst ^ (row & 7);
      const __hip_bfloat16* g = BT + (size_t)(bn + row) * K + k0 + ksrc * 8;
      gload_lds16(g, sB[buf] + (i * 512 + wave_base) * 8);
    }
  };

  auto compute = [&](int buf) {
    const __hip_bfloat16* pA = sA[buf];
    const __hip_bfloat16* pB = sB[buf];
#pragma unroll
    for (int kb = 0; kb < 2; ++kb) {
      bf16x8 a[MI], b[NI];
      const int kblk = kb * 4 + l4;
#pragma unroll
      for (int mi = 0; mi < MI; ++mi) {
        const int row = wm + mi * 16 + l15;
        a[mi] = *(const bf16x8*)(pA + row * 64 + ((kblk ^ (row & 7)) * 8));
      }
#pragma unroll
      for (int ni = 0; ni < NI; ++ni) {
        const int row = wn + ni * 16 + l15;
        b[ni] = *(const bf16x8*)(pB + row * 64 + ((kblk ^ (row & 7)) * 8));
      }
#pragma unroll
      for (int mi = 0; mi < MI; ++mi)
#pragma unroll
        for (int ni = 0; ni < NI; ++ni)
          acc[mi][ni] = __builtin_amdgcn_mfma_f32_16x16x32_bf16(a[mi], b[ni], acc[mi][ni], 0, 0, 0);
    }
  };

  const int nt = K >> 6;
  stage(0, 0);
  stage(1, 1);
  int cur = 0;
  for (int tt = 0; tt < nt; ++tt) {
    // own tile-tt loads landed (tile tt+1's 7 may remain in flight)
    if (tt < nt - 1) asm volatile("s_waitcnt vmcnt(7)" ::: "memory");
    else             asm volatile("s_waitcnt vmcnt(0)" ::: "memory");
    __builtin_amdgcn_sched_barrier(0);
    __builtin_amdgcn_s_barrier();       // all waves' tile-tt loads now in LDS
    __builtin_amdgcn_sched_barrier(0);
    compute(cur);
    if (tt + 2 < nt) {
      __builtin_amdgcn_sched_barrier(0);
      __builtin_amdgcn_s_barrier();     // all waves done reading buf cur
      __builtin_amdgcn_sched_barrier(0);
      stage(cur, tt + 2);               // overwrite cur with tile tt+2
    }
    cur ^= 1;
  }

#pragma unroll
  for (int mi = 0; mi < MI; ++mi) {
    const int mrow = bm + wm + mi * 16 + l4 * 4;
#pragma unroll
    for (int ni = 0; ni < NI; ++ni) {
      const int col = bn + wn + ni * 16 + l15;
      const float bv = bias[col];
#pragma unroll
      for (int r2 = 0; r2 < 4; ++r2) {
        const size_t idx = (size_t)(mrow + r2) * N + col;
        float v = acc[mi][ni][r2] + bv;
        if (EPI == 1) v += res[idx];
        if (EPI == 2) v = 0.5f * v * (1.0f + erff(v * 0.70710678118654752f));
        stf(C, idx, v);
      }
    }
  }
}

// ---------- MFMA windowed attention: 1 wave per (window, head) ----------
__global__ __launch_bounds__(64) void attn_mfma_kernel(
    const __hip_bfloat16* __restrict__ qkv, const float* __restrict__ biases,
    __hip_bfloat16* __restrict__ o) {
  __shared__ __hip_bfloat16 sQK[2][64][40];
  __shared__ __hip_bfloat16 sVT[32][72];
  __hip_bfloat16 (*sP)[72] = (__hip_bfloat16(*)[72])(&sQK[0][0][0]);

  const int wid  = blockIdx.x / 18;
  const int head = blockIdx.x - wid * 18;
  const int b  = wid >> 4;
  const int wi = wid & 15;
  const int wh = wi >> 2, wwc = wi & 3;
  const int lane = threadIdx.x;
  const int l15 = lane & 15, l4 = lane >> 4;

  {
    const __hip_bfloat16* basep = qkv + (size_t)head * 96;
    for (int idx = lane; idx < 49 * 12; idx += 64) {
      const int tkn = idx / 12, part = idx - tkn * 12;
      const int r = tkn / 7, c = tkn - r * 7;
      const size_t row = (size_t)b * 784 + (size_t)((wh * 7 + r) * 28 + wwc * 7 + c);
      bf16x8 v = *(const bf16x8*)(basep + row * 1728 + part * 8);
      if (part < 4)      *(bf16x8*)&sQK[0][tkn][part * 8] = v;
      else if (part < 8) *(bf16x8*)&sQK[1][tkn][(part - 4) * 8] = v;
      else {
        const int d0 = (part - 8) * 8;
        const short* sv = (const short*)&v;
#pragma unroll
        for (int e = 0; e < 8; ++e)
          sVT[d0 + e][tkn] = *(const __hip_bfloat16*)&sv[e];
      }
    }
    for (int idx = lane; idx < 32 * 15; idx += 64) {
      const int d = idx / 15, tt = 49 + (idx - d * 15);
      sVT[d][tt] = __float2bfloat16(0.0f);
    }
  }
  __syncthreads();

  f32x4 acc[4][4];
#pragma unroll
  for (int mi = 0; mi < 4; ++mi)
#pragma unroll
    for (int ni = 0; ni < 4; ++ni) acc[mi][ni] = (f32x4){0.f, 0.f, 0.f, 0.f};
  {
    bf16x8 aq[4], bk[4];
#pragma unroll
    for (int mi = 0; mi < 4; ++mi) aq[mi] = *(const bf16x8*)&sQK[0][mi * 16 + l15][l4 * 8];
#pragma unroll
    for (int ni = 0; ni < 4; ++ni) bk[ni] = *(const bf16x8*)&sQK[1][ni * 16 + l15][l4 * 8];
#pragma unroll
    for (int mi = 0; mi < 4; ++mi)
#pragma unroll
      for (int ni = 0; ni < 4; ++ni)
        acc[mi][ni] = __builtin_amdgcn_mfma_f32_16x16x32_bf16(aq[mi], bk[ni], acc[mi][ni], 0, 0, 0);
  }
  __syncthreads();

  const float scale = 0.17677669529663687f;
  const float* btab = biases + head * 49;
#pragma unroll
  for (int mi = 0; mi < 4; ++mi) {
#pragma unroll
    for (int rr = 0; rr < 4; ++rr) {
      const int i = mi * 16 + l4 * 4 + rr;
      const int ic = i < 49 ? i : 0;
      const int ri = ic / 7, ci = ic - ri * 7;
      float s[4];
#pragma unroll
      for (int ni = 0; ni < 4; ++ni) {
        const int j = ni * 16 + l15;
        if (j < 49) {
          const int rj = j / 7, cj = j - rj * 7;
          s[ni] = acc[mi][ni][rr] * scale + btab[__builtin_abs(ri - rj) * 7 + __builtin_abs(ci - cj)];
        } else {
          s[ni] = -1e30f;
        }
      }
      float m = fmaxf(fmaxf(s[0], s[1]), fmaxf(s[2], s[3]));
#pragma unroll
      for (int d = 1; d < 16; d <<= 1) m = fmaxf(m, __shfl_xor(m, d));
      float sum = 0.f;
#pragma unroll
      for (int ni = 0; ni < 4; ++ni) { s[ni] = __expf(s[ni] - m); sum += s[ni]; }
#pragma unroll
      for (int d = 1; d < 16; d <<= 1) sum += __shfl_xor(sum, d);
      const float inv = 1.0f / sum;
#pragma unroll
      for (int ni = 0; ni < 4; ++ni)
        sP[i][ni * 16 + l15] = __float2bfloat16(s[ni] * inv);
    }
  }
  __syncthreads();

  f32x4 oacc[4][2];
#pragma unroll
  for (int mi = 0; mi < 4; ++mi)
#pragma unroll
    for (int ni = 0; ni < 2; ++ni) oacc[mi][ni] = (f32x4){0.f, 0.f, 0.f, 0.f};
#pragma unroll
  for (int kb = 0; kb < 2; ++kb) {
    bf16x8 ap[4], bv[2];
#pragma unroll
    for (int mi = 0; mi < 4; ++mi) ap[mi] = *(const bf16x8*)&sP[mi * 16 + l15][kb * 32 + l4 * 8];
#pragma unroll
    for (int ni = 0; ni < 2; ++ni) bv[ni] = *(const bf16x8*)&sVT[ni * 16 + l15][kb * 32 + l4 * 8];
#pragma unroll
    for (int mi = 0; mi < 4; ++mi)
#pragma unroll
      for (int ni = 0; ni < 2; ++ni)
        oacc[mi][ni] = __builtin_amdgcn_mfma_f32_16x16x32_bf16(ap[mi], bv[ni], oacc[mi][ni], 0, 0, 0);
  }

#pragma unroll
  for (int mi = 0; mi < 4; ++mi) {
#pragma unroll
    for (int rr = 0; rr < 4; ++rr) {
      const int i = mi * 16 + l4 * 4 + rr;
      if (i < 49) {
        const int r = i / 7, c = i - r * 7;
        const size_t grow = (size_t)b * 784 + (size_t)((wh * 7 + r) * 28 + wwc * 7 + c);
#pragma unroll
        for (int ni = 0; ni < 2; ++ni)
          o[grow * 576 + head * 32 + ni * 16 + l15] = __float2bfloat16(oacc[mi][ni][rr]);
      }
    }
  }
}

// ---------- depthwise 3x3 conv + folded BN, float4 over channels ----------
__global__ void conv_bn_kernel(const float* __restrict__ x1, const float* __restrict__ wT,
                               const float* __restrict__ st, float* __restrict__ x2) {
  const size_t total = (size_t)32 * 784 * 144;
  const size_t idx = (size_t)blockIdx.x * 256 + threadIdx.x;
  if (idx >= total) return;
  const int c4 = (int)(idx % 144);
  const size_t p = idx / 144;
  const int pix = (int)(p % 784);
  const int b = (int)(p / 784);
  const int i = pix / 28, j = pix - (pix / 28) * 28;
  const int c = c4 * 4;
  f32x4 acc = (f32x4){0.f, 0.f, 0.f, 0.f};
#pragma unroll
  for (int dh = -1; dh <= 1; ++dh) {
#pragma unroll
    for (int dw = -1; dw <= 1; ++dw) {
      const int ii = i + dh, jj = j + dw;
      if (ii >= 0 && ii < 28 && jj >= 0 && jj < 28) {
        const f32x4 v = *(const f32x4*)&x1[((size_t)b * 784 + ii * 28 + jj) * 576 + c];
        const f32x4 wv = *(const f32x4*)&wT[((dh + 1) * 3 + (dw + 1)) * 576 + c];
        acc += v * wv;
      }
    }
  }
  const f32x4 s = *(const f32x4*)&st[c];
  const f32x4 tt = *(const f32x4*)&st[576 + c];
  *(f32x4*)&x2[((size_t)b * 784 + pix) * 576 + c] = acc * s + tt;
}

// ---------- launch ----------
extern "C" void kernel_launch(void* const* d_in, const int* in_sizes, int n_in,
                              void* d_out, int out_size, void* d_ws, size_t ws_size,
                              hipStream_t stream) {
  (void)in_sizes; (void)n_in; (void)out_size; (void)ws_size;
  const float* x      = (const float*)d_in[0];
  const float* ln1g   = (const float*)d_in[1];
  const float* ln1b   = (const float*)d_in[2];
  const float* qkv_w  = (const float*)d_in[3];
  const float* qkv_b  = (const float*)d_in[4];
  const float* biases = (const float*)d_in[5];
  const float* proj_w = (const float*)d_in[6];
  const float* proj_b = (const float*)d_in[7];
  const float* conv_w = (const float*)d_in[8];
  const float* bng    = (const float*)d_in[9];
  const float* bnb    = (const float*)d_in[10];
  const float* bnm    = (const float*)d_in[11];
  const float* bnv    = (const float*)d_in[12];
  const float* ln2g   = (const float*)d_in[13];
  const float* ln2b   = (const float*)d_in[14];
  const float* fc1_w  = (const float*)d_in[15];
  const float* fc1_b  = (const float*)d_in[16];
  const float* fc2_w  = (const float*)d_in[17];
  const float* fc2_b  = (const float*)d_in[18];
  float* out = (float*)d_out;

  const int M = 25088;
  char* ws = (char*)d_ws;
  // Workspace:
  //   A [0, 57802752)           : x2 f32 (M x 576)
  //   B [57802752, +115605504)  : qkv bf16 (Mx1728) -> x1 f32 (Mx576) -> hm bf16 (Mx2304)
  //   C [173408256, +28901376)  : xn1 bf16 -> o bf16 -> xn2 bf16
  //   D [202309632, +7962624)   : transposed bf16 weights
  //   E [210272256, +25344)     : conv wT (9x576 f32) + st (2x576 f32)
  float* x2 = (float*)ws;
  char* regB = ws + 57802752;
  __hip_bfloat16* qkvb = (__hip_bfloat16*)regB;
  float*          x1   = (float*)regB;
  __hip_bfloat16* hm   = (__hip_bfloat16*)regB;
  char* regC = ws + 173408256;
  __hip_bfloat16* xn1  = (__hip_bfloat16*)regC;
  __hip_bfloat16* obuf = (__hip_bfloat16*)regC;
  __hip_bfloat16* xn2  = (__hip_bfloat16*)regC;
  char* regD = ws + 202309632;
  __hip_bfloat16* qkvT = (__hip_bfloat16*)regD;
  __hip_bfloat16* projT = (__hip_bfloat16*)(regD + 1990656);
  __hip_bfloat16* fc1T  = (__hip_bfloat16*)(regD + 1990656 + 663552);
  __hip_bfloat16* fc2T  = (__hip_bfloat16*)(regD + 1990656 + 663552 + 2654208);
  float* convT = (float*)(ws + 210272256);
  float* convST = convT + 9 * 576;

  // weight prep
  wt_kernel<<<dim3(1728 / 32, 576 / 32), 256, 0, stream>>>(qkv_w, qkvT, 576, 1728);
  wt_kernel<<<dim3(576 / 32, 576 / 32), 256, 0, stream>>>(proj_w, projT, 576, 576);
  wt_kernel<<<dim3(2304 / 32, 576 / 32), 256, 0, stream>>>(fc1_w, fc1T, 576, 2304);
  wt_kernel<<<dim3(576 / 32, 2304 / 32), 256, 0, stream>>>(fc2_w, fc2T, 2304, 576);
  convprep_kernel<<<(576 * 9 + 255) / 256, 256, 0, stream>>>(conv_w, bng, bnb, bnm, bnv, convT, convST);

  // 1. xn1 = LN1(x) bf16
  ln_bf16_kernel<<<M / 4, 256, 0, stream>>>(x, ln1g, ln1b, xn1);
  // 2. qkv = xn1 @ qkv_w + qkv_b (bf16 out); grid 98 x (1728/192)
  gemm_bt<0, __hip_bfloat16><<<98 * 9, 512, 0, stream>>>(xn1, qkvT, qkv_b, nullptr, qkvb, M, 1728, 576);
  // 3. attention (MFMA, 1 wave per window-head)
  attn_mfma_kernel<<<512 * 18, 64, 0, stream>>>(qkvb, biases, obuf);
  // 4. x1 = x + (o @ proj_w + proj_b); grid 98 x 3
  gemm_bt<1, float><<<98 * 3, 512, 0, stream>>>(obuf, projT, proj_b, x, x1, M, 576, 576);
  // 5. x2 = BN(dwconv(x1))
  conv_bn_kernel<<<(32 * 784 * 144 + 255) / 256, 256, 0, stream>>>(x1, convT, convST, x2);
  // 6. xn2 = LN2(x2) bf16
  ln_bf16_kernel<<<M / 4, 256, 0, stream>>>(x2, ln2g, ln2b, xn2);
  // 7. hm = gelu(xn2 @ fc1_w + fc1_b) bf16; grid 98 x 12
  gemm_bt<2, __hip_bfloat16><<<98 * 12, 512, 0, stream>>>(xn2, fc1T, fc1_b, nullptr, hm, M, 2304, 576);
  // 8. out = x2 + (hm @ fc2_w + fc2_b); grid 98 x 3
  gemm_bt<1, float><<<98 * 3, 512, 0, stream>>>(hm, fc2T, fc2_b, x2, out, M, 576, 2304);
}

// Round 10
// 561.059 us; speedup vs baseline: 1.0013x; 1.0013x over previous
//
#include <hip/hip_runtime.h>
#include <hip/hip_bf16.h>

typedef __attribute__((ext_vector_type(8))) short bf16x8;
typedef __attribute__((ext_vector_type(4))) float f32x4;

static __device__ __forceinline__ void stf(float* p, size_t i, float v) { p[i] = v; }
static __device__ __forceinline__ void stf(__hip_bfloat16* p, size_t i, float v) { p[i] = __float2bfloat16(v); }

static __device__ __forceinline__ void gload_lds16(const void* g, void* l) {
  __builtin_amdgcn_global_load_lds((const __attribute__((address_space(1))) void*)g,
                                   (__attribute__((address_space(3))) void*)l, 16, 0, 0);
}
static __device__ __forceinline__ void vm2() { asm volatile("s_waitcnt vmcnt(2)" ::: "memory"); }
static __device__ __forceinline__ void vm0() { asm volatile("s_waitcnt vmcnt(0)" ::: "memory"); }
static __device__ __forceinline__ void lgkm0() {
  asm volatile("s_waitcnt lgkmcnt(0)" ::: "memory");
  __builtin_amdgcn_sched_barrier(0);
}
static __device__ __forceinline__ void barrier() {
  __builtin_amdgcn_sched_barrier(0);
  __builtin_amdgcn_s_barrier();
  __builtin_amdgcn_sched_barrier(0);
}

// ---------- weight transpose + bf16 convert: W[K][N] f32 -> WT[N][K] bf16 ----------
__global__ void wt_kernel(const float* __restrict__ W, __hip_bfloat16* __restrict__ WT, int K, int N) {
  __shared__ float tile[32][33];
  const int kb = blockIdx.y * 32, nb = blockIdx.x * 32;
  const int tx = threadIdx.x & 31, ty = threadIdx.x >> 5;
#pragma unroll
  for (int i = 0; i < 4; ++i)
    tile[ty + i * 8][tx] = W[(size_t)(kb + ty + i * 8) * N + nb + tx];
  __syncthreads();
#pragma unroll
  for (int i = 0; i < 4; ++i)
    WT[(size_t)(nb + ty + i * 8) * K + kb + tx] = __float2bfloat16(tile[tx][ty + i * 8]);
}

// ---------- conv prep ----------
__global__ void convprep_kernel(const float* __restrict__ w, const float* __restrict__ bng,
                                const float* __restrict__ bnb, const float* __restrict__ bnm,
                                const float* __restrict__ bnv, float* __restrict__ wT,
                                float* __restrict__ st) {
  const int i = blockIdx.x * 256 + threadIdx.x;
  if (i < 576 * 9) {
    const int t = i / 576, c = i - t * 576;
    wT[i] = w[c * 9 + t];
  }
  if (i < 576) {
    const float s = rsqrtf(bnv[i] + 1e-5f) * bng[i];
    st[i] = s;
    st[576 + i] = bnb[i] - bnm[i] * s;
  }
}

// ---------- fused LN -> bf16 ----------
__global__ void ln_bf16_kernel(const float* __restrict__ x, const float* __restrict__ g,
                               const float* __restrict__ b, __hip_bfloat16* __restrict__ y) {
  const int row = blockIdx.x * 4 + (threadIdx.x >> 6);
  const int lane = threadIdx.x & 63;
  const float* p = x + (size_t)row * 576;
  float vals[9];
  float s = 0.f, ss = 0.f;
#pragma unroll
  for (int i = 0; i < 9; ++i) {
    float v = p[lane + i * 64];
    vals[i] = v; s += v; ss += v * v;
  }
#pragma unroll
  for (int o = 32; o; o >>= 1) { s += __shfl_down(s, o); ss += __shfl_down(ss, o); }
  s = __shfl(s, 0); ss = __shfl(ss, 0);
  const float m = s * (1.f / 576.f);
  const float rstd = rsqrtf(ss * (1.f / 576.f) - m * m + 1e-5f);
  __hip_bfloat16* q = y + (size_t)row * 576;
#pragma unroll
  for (int i = 0; i < 9; ++i) {
    const int c = lane + i * 64;
    q[c] = __float2bfloat16((vals[i] - m) * rstd * g[c] + b[c]);
  }
}

// ---------- 8-phase MFMA GEMM (T2+T3+T4+T5): C = epi(A @ BT^T + bias) ----------
// BM=256, BN=192, BK=64, 512 thr (8 waves 2Mx4N, wave tile 128x48).
// Staging: 7 units of 8KB (B0,B1,B2 = 64 B-rows each; A0..A3 = 64 A-rows each).
// Issue order B0,B1,B2,A0,A2,A1,A3 so the 5 OLDEST in flight are exactly the
// units needed at the next iteration's P0 (all B + A0 + A2) -> vmcnt(2) suffices;
// A1,A3 (needed at P1) are covered by the P0-end vmcnt(2). Never drain to 0 in
// steady state. Per K-tile: 4 phases {ds_read subtile; stage 1-2 units; barrier;
// lgkmcnt(0); setprio(1); 12 MFMA; setprio(0); barrier}.
// EPI: 0 none, 1 +res, 2 exact GELU
template <int EPI, typename TO>
__global__ __launch_bounds__(512, 2) void gemm8(
    const __hip_bfloat16* __restrict__ A, const __hip_bfloat16* __restrict__ BT,
    const float* __restrict__ bias, const float* __restrict__ res, TO* __restrict__ C,
    int M, int N, int K) {
  constexpr int BM = 256, BN = 192;
  __shared__ __hip_bfloat16 sA[2][BM * 64];
  __shared__ __hip_bfloat16 sB[2][BN * 64];
  const int t = threadIdx.x;
  const int lane = t & 63;
  const int w = t >> 6;
  const int nwg = gridDim.x;
  const int qq = nwg >> 3, r = nwg & 7;
  const int xcd = blockIdx.x & 7, lidx = blockIdx.x >> 3;
  const int wgid = (xcd < r ? xcd * (qq + 1) : r * (qq + 1) + (xcd - r) * qq) + lidx;
  const int nx = N / BN;
  const int bm = (wgid / nx) * BM, bn = (wgid % nx) * BN;
  const int wm = (w >> 2) * 128, wn = (w & 3) * 48;
  const int l15 = lane & 15, l4 = lane >> 4;
  const int wave_base = t & ~63;

  f32x4 acc[8][3];
#pragma unroll
  for (int mi = 0; mi < 8; ++mi)
#pragma unroll
    for (int ni = 0; ni < 3; ++ni) acc[mi][ni] = (f32x4){0.f, 0.f, 0.f, 0.f};

  auto stA = [&](int buf, int kt, int u) {
    const int slot = u * 512 + t;
    const int row = slot >> 3, kst = slot & 7;
    const int ksrc = kst ^ (row & 7);
    gload_lds16(A + (size_t)(bm + row) * K + (kt << 6) + ksrc * 8,
                sA[buf] + (u * 512 + wave_base) * 8);
  };
  auto stB = [&](int buf, int kt, int u) {
    const int slot = u * 512 + t;
    const int row = slot >> 3, kst = slot & 7;
    const int ksrc = kst ^ (row & 7);
    gload_lds16(BT + (size_t)(bn + row) * K + (kt << 6) + ksrc * 8,
                sB[buf] + (u * 512 + wave_base) * 8);
  };

  bf16x8 a[4], b[3];
  auto lda = [&](int c, int kb, int mh) {
#pragma unroll
    for (int i = 0; i < 4; ++i) {
      const int row = wm + (mh * 4 + i) * 16 + l15;
      const int kblk = kb * 4 + l4;
      a[i] = *(const bf16x8*)(&sA[c][row * 64 + ((kblk ^ (row & 7)) * 8)]);
    }
  };
  auto ldb = [&](int c, int kb) {
#pragma unroll
    for (int ni = 0; ni < 3; ++ni) {
      const int row = wn + ni * 16 + l15;
      const int kblk = kb * 4 + l4;
      b[ni] = *(const bf16x8*)(&sB[c][row * 64 + ((kblk ^ (row & 7)) * 8)]);
    }
  };
  auto mm = [&](int mh) {
#pragma unroll
    for (int i = 0; i < 4; ++i)
#pragma unroll
      for (int ni = 0; ni < 3; ++ni)
        acc[mh * 4 + i][ni] =
            __builtin_amdgcn_mfma_f32_16x16x32_bf16(a[i], b[ni], acc[mh * 4 + i][ni], 0, 0, 0);
  };

  // prologue: tile 0, order B0,B1,B2,A0,A2,A1,A3
  stB(0, 0, 0); stB(0, 0, 1); stB(0, 0, 2);
  stA(0, 0, 0); stA(0, 0, 2); stA(0, 0, 1); stA(0, 0, 3);

  const int nt = K >> 6;
  for (int tt = 0; tt < nt; ++tt) {
    const int c = tt & 1, n1 = c ^ 1;
    const int kt1 = tt + 1;
    const bool pre = kt1 < nt;
    vm2();          // oldest 5 of tile tt landed: B0,B1,B2,A0,A2
    barrier();
    // P0: kb0, rows mh0 (units A0/A2) + B kb0
    lda(c, 0, 0); ldb(c, 0);
    if (pre) { stB(n1, kt1, 0); stB(n1, kt1, 1); }
    barrier(); lgkm0();
    __builtin_amdgcn_s_setprio(1); mm(0); __builtin_amdgcn_s_setprio(0);
    if (pre) vm2(); else vm0();   // A1,A3 of tile tt landed
    barrier();
    // P1: kb0, rows mh1 (units A1/A3)
    lda(c, 0, 1);
    if (pre) { stB(n1, kt1, 2); stA(n1, kt1, 0); }
    barrier(); lgkm0();
    __builtin_amdgcn_s_setprio(1); mm(1); __builtin_amdgcn_s_setprio(0);
    barrier();
    // P2: kb1, rows mh0
    lda(c, 1, 0); ldb(c, 1);
    if (pre) { stA(n1, kt1, 2); stA(n1, kt1, 1); }
    barrier(); lgkm0();
    __builtin_amdgcn_s_setprio(1); mm(0); __builtin_amdgcn_s_setprio(0);
    barrier();
    // P3: kb1, rows mh1
    lda(c, 1, 1);
    if (pre) { stA(n1, kt1, 3); }
    barrier(); lgkm0();
    __builtin_amdgcn_s_setprio(1); mm(1); __builtin_amdgcn_s_setprio(0);
    // next iteration top: vm2(); barrier();
  }

#pragma unroll
  for (int mi = 0; mi < 8; ++mi) {
    const int mrow = bm + wm + mi * 16 + l4 * 4;
#pragma unroll
    for (int ni = 0; ni < 3; ++ni) {
      const int col = bn + wn + ni * 16 + l15;
      const float bv = bias[col];
#pragma unroll
      for (int r2 = 0; r2 < 4; ++r2) {
        const size_t idx = (size_t)(mrow + r2) * N + col;
        float v = acc[mi][ni][r2] + bv;
        if (EPI == 1) v += res[idx];
        if (EPI == 2) v = 0.5f * v * (1.0f + erff(v * 0.70710678118654752f));
        stf(C, idx, v);
      }
    }
  }
}

// ---------- coarse counted-vmcnt GEMM (R9) for proj / fc2 ----------
template <int EPI, typename TO>
__global__ __launch_bounds__(512, 1) void gemm_bt(
    const __hip_bfloat16* __restrict__ A, const __hip_bfloat16* __restrict__ BT,
    const float* __restrict__ bias, const float* __restrict__ res, TO* __restrict__ C,
    int M, int N, int K) {
  constexpr int BM = 256, BN = 192;
  constexpr int MI = 8, NI = 3;
  constexpr int AI = 4, BI = 3;
  __shared__ __hip_bfloat16 sA[2][BM * 64];
  __shared__ __hip_bfloat16 sB[2][BN * 64];
  const int t = threadIdx.x;
  const int lane = t & 63;
  const int w = t >> 6;
  const int nwg = gridDim.x;
  const int qq = nwg >> 3, r = nwg & 7;
  const int xcd = blockIdx.x & 7, lidx = blockIdx.x >> 3;
  const int wgid = (xcd < r ? xcd * (qq + 1) : r * (qq + 1) + (xcd - r) * qq) + lidx;
  const int nx = N / BN;
  const int bm = (wgid / nx) * BM, bn = (wgid % nx) * BN;
  const int wm = (w >> 2) * 128, wn = (w & 3) * 48;
  const int l15 = lane & 15, l4 = lane >> 4;

  f32x4 acc[MI][NI];
#pragma unroll
  for (int mi = 0; mi < MI; ++mi)
#pragma unroll
    for (int ni = 0; ni < NI; ++ni) acc[mi][ni] = (f32x4){0.f, 0.f, 0.f, 0.f};

  const int wave_base = t & ~63;

  auto stage = [&](int buf, int kt) {
    const int k0 = kt << 6;
#pragma unroll
    for (int i = 0; i < AI; ++i) {
      const int slot = i * 512 + t;
      const int row = slot >> 3, kst = slot & 7;
      const int ksrc = kst ^ (row & 7);
      gload_lds16(A + (size_t)(bm + row) * K + k0 + ksrc * 8, sA[buf] + (i * 512 + wave_base) * 8);
    }
#pragma unroll
    for (int i = 0; i < BI; ++i) {
      const int slot = i * 512 + t;
      const int row = slot >> 3, kst = slot & 7;
      const int ksrc = kst ^ (row & 7);
      gload_lds16(BT + (size_t)(bn + row) * K + k0 + ksrc * 8, sB[buf] + (i * 512 + wave_base) * 8);
    }
  };

  auto compute = [&](int buf) {
    const __hip_bfloat16* pA = sA[buf];
    const __hip_bfloat16* pB = sB[buf];
#pragma unroll
    for (int kb = 0; kb < 2; ++kb) {
      bf16x8 a[MI], b[NI];
      const int kblk = kb * 4 + l4;
#pragma unroll
      for (int mi = 0; mi < MI; ++mi) {
        const int row = wm + mi * 16 + l15;
        a[mi] = *(const bf16x8*)(pA + row * 64 + ((kblk ^ (row & 7)) * 8));
      }
#pragma unroll
      for (int ni = 0; ni < NI; ++ni) {
        const int row = wn + ni * 16 + l15;
        b[ni] = *(const bf16x8*)(pB + row * 64 + ((kblk ^ (row & 7)) * 8));
      }
#pragma unroll
      for (int mi = 0; mi < MI; ++mi)
#pragma unroll
        for (int ni = 0; ni < NI; ++ni)
          acc[mi][ni] = __builtin_amdgcn_mfma_f32_16x16x32_bf16(a[mi], b[ni], acc[mi][ni], 0, 0, 0);
    }
  };

  const int nt = K >> 6;
  stage(0, 0);
  stage(1, 1);
  int cur = 0;
  for (int tt = 0; tt < nt; ++tt) {
    if (tt < nt - 1) asm volatile("s_waitcnt vmcnt(7)" ::: "memory");
    else             asm volatile("s_waitcnt vmcnt(0)" ::: "memory");
    barrier();
    compute(cur);
    if (tt + 2 < nt) {
      barrier();
      stage(cur, tt + 2);
    }
    cur ^= 1;
  }

#pragma unroll
  for (int mi = 0; mi < MI; ++mi) {
    const int mrow = bm + wm + mi * 16 + l4 * 4;
#pragma unroll
    for (int ni = 0; ni < NI; ++ni) {
      const int col = bn + wn + ni * 16 + l15;
      const float bv = bias[col];
#pragma unroll
      for (int r2 = 0; r2 < 4; ++r2) {
        const size_t idx = (size_t)(mrow + r2) * N + col;
        float v = acc[mi][ni][r2] + bv;
        if (EPI == 1) v += res[idx];
        if (EPI == 2) v = 0.5f * v * (1.0f + erff(v * 0.70710678118654752f));
        stf(C, idx, v);
      }
    }
  }
}

// ---------- MFMA windowed attention: 1 wave per (window, head) ----------
__global__ __launch_bounds__(64) void attn_mfma_kernel(
    const __hip_bfloat16* __restrict__ qkv, const float* __restrict__ biases,
    __hip_bfloat16* __restrict__ o) {
  __shared__ __hip_bfloat16 sQK[2][64][40];
  __shared__ __hip_bfloat16 sVT[32][72];
  __hip_bfloat16 (*sP)[72] = (__hip_bfloat16(*)[72])(&sQK[0][0][0]);

  const int wid  = blockIdx.x / 18;
  const int head = blockIdx.x - wid * 18;
  const int b  = wid >> 4;
  const int wi = wid & 15;
  const int wh = wi >> 2, wwc = wi & 3;
  const int lane = threadIdx.x;
  const int l15 = lane & 15, l4 = lane >> 4;

  {
    const __hip_bfloat16* basep = qkv + (size_t)head * 96;
    for (int idx = lane; idx < 49 * 12; idx += 64) {
      const int tkn = idx / 12, part = idx - tkn * 12;
      const int r = tkn / 7, c = tkn - r * 7;
      const size_t row = (size_t)b * 784 + (size_t)((wh * 7 + r) * 28 + wwc * 7 + c);
      bf16x8 v = *(const bf16x8*)(basep + row * 1728 + part * 8);
      if (part < 4)      *(bf16x8*)&sQK[0][tkn][part * 8] = v;
      else if (part < 8) *(bf16x8*)&sQK[1][tkn][(part - 4) * 8] = v;
      else {
        const int d0 = (part - 8) * 8;
        const short* sv = (const short*)&v;
#pragma unroll
        for (int e = 0; e < 8; ++e)
          sVT[d0 + e][tkn] = *(const __hip_bfloat16*)&sv[e];
      }
    }
    for (int idx = lane; idx < 32 * 15; idx += 64) {
      const int d = idx / 15, tt = 49 + (idx - d * 15);
      sVT[d][tt] = __float2bfloat16(0.0f);
    }
  }
  __syncthreads();

  f32x4 acc[4][4];
#pragma unroll
  for (int mi = 0; mi < 4; ++mi)
#pragma unroll
    for (int ni = 0; ni < 4; ++ni) acc[mi][ni] = (f32x4){0.f, 0.f, 0.f, 0.f};
  {
    bf16x8 aq[4], bk[4];
#pragma unroll
    for (int mi = 0; mi < 4; ++mi) aq[mi] = *(const bf16x8*)&sQK[0][mi * 16 + l15][l4 * 8];
#pragma unroll
    for (int ni = 0; ni < 4; ++ni) bk[ni] = *(const bf16x8*)&sQK[1][ni * 16 + l15][l4 * 8];
#pragma unroll
    for (int mi = 0; mi < 4; ++mi)
#pragma unroll
      for (int ni = 0; ni < 4; ++ni)
        acc[mi][ni] = __builtin_amdgcn_mfma_f32_16x16x32_bf16(aq[mi], bk[ni], acc[mi][ni], 0, 0, 0);
  }
  __syncthreads();

  const float scale = 0.17677669529663687f;
  const float* btab = biases + head * 49;
#pragma unroll
  for (int mi = 0; mi < 4; ++mi) {
#pragma unroll
    for (int rr = 0; rr < 4; ++rr) {
      const int i = mi * 16 + l4 * 4 + rr;
      const int ic = i < 49 ? i : 0;
      const int ri = ic / 7, ci = ic - ri * 7;
      float s[4];
#pragma unroll
      for (int ni = 0; ni < 4; ++ni) {
        const int j = ni * 16 + l15;
        if (j < 49) {
          const int rj = j / 7, cj = j - rj * 7;
          s[ni] = acc[mi][ni][rr] * scale + btab[__builtin_abs(ri - rj) * 7 + __builtin_abs(ci - cj)];
        } else {
          s[ni] = -1e30f;
        }
      }
      float m = fmaxf(fmaxf(s[0], s[1]), fmaxf(s[2], s[3]));
#pragma unroll
      for (int d = 1; d < 16; d <<= 1) m = fmaxf(m, __shfl_xor(m, d));
      float sum = 0.f;
#pragma unroll
      for (int ni = 0; ni < 4; ++ni) { s[ni] = __expf(s[ni] - m); sum += s[ni]; }
#pragma unroll
      for (int d = 1; d < 16; d <<= 1) sum += __shfl_xor(sum, d);
      const float inv = 1.0f / sum;
#pragma unroll
      for (int ni = 0; ni < 4; ++ni)
        sP[i][ni * 16 + l15] = __float2bfloat16(s[ni] * inv);
    }
  }
  __syncthreads();

  f32x4 oacc[4][2];
#pragma unroll
  for (int mi = 0; mi < 4; ++mi)
#pragma unroll
    for (int ni = 0; ni < 2; ++ni) oacc[mi][ni] = (f32x4){0.f, 0.f, 0.f, 0.f};
#pragma unroll
  for (int kb = 0; kb < 2; ++kb) {
    bf16x8 ap[4], bv[2];
#pragma unroll
    for (int mi = 0; mi < 4; ++mi) ap[mi] = *(const bf16x8*)&sP[mi * 16 + l15][kb * 32 + l4 * 8];
#pragma unroll
    for (int ni = 0; ni < 2; ++ni) bv[ni] = *(const bf16x8*)&sVT[ni * 16 + l15][kb * 32 + l4 * 8];
#pragma unroll
    for (int mi = 0; mi < 4; ++mi)
#pragma unroll
      for (int ni = 0; ni < 2; ++ni)
        oacc[mi][ni] = __builtin_amdgcn_mfma_f32_16x16x32_bf16(ap[mi], bv[ni], oacc[mi][ni], 0, 0, 0);
  }

#pragma unroll
  for (int mi = 0; mi < 4; ++mi) {
#pragma unroll
    for (int rr = 0; rr < 4; ++rr) {
      const int i = mi * 16 + l4 * 4 + rr;
      if (i < 49) {
        const int r = i / 7, c = i - r * 7;
        const size_t grow = (size_t)b * 784 + (size_t)((wh * 7 + r) * 28 + wwc * 7 + c);
#pragma unroll
        for (int ni = 0; ni < 2; ++ni)
          o[grow * 576 + head * 32 + ni * 16 + l15] = __float2bfloat16(oacc[mi][ni][rr]);
      }
    }
  }
}

// ---------- depthwise 3x3 conv + folded BN, float4 over channels ----------
__global__ void conv_bn_kernel(const float* __restrict__ x1, const float* __restrict__ wT,
                               const float* __restrict__ st, float* __restrict__ x2) {
  const size_t total = (size_t)32 * 784 * 144;
  const size_t idx = (size_t)blockIdx.x * 256 + threadIdx.x;
  if (idx >= total) return;
  const int c4 = (int)(idx % 144);
  const size_t p = idx / 144;
  const int pix = (int)(p % 784);
  const int b = (int)(p / 784);
  const int i = pix / 28, j = pix - (pix / 28) * 28;
  const int c = c4 * 4;
  f32x4 acc = (f32x4){0.f, 0.f, 0.f, 0.f};
#pragma unroll
  for (int dh = -1; dh <= 1; ++dh) {
#pragma unroll
    for (int dw = -1; dw <= 1; ++dw) {
      const int ii = i + dh, jj = j + dw;
      if (ii >= 0 && ii < 28 && jj >= 0 && jj < 28) {
        const f32x4 v = *(const f32x4*)&x1[((size_t)b * 784 + ii * 28 + jj) * 576 + c];
        const f32x4 wv = *(const f32x4*)&wT[((dh + 1) * 3 + (dw + 1)) * 576 + c];
        acc += v * wv;
      }
    }
  }
  const f32x4 s = *(const f32x4*)&st[c];
  const f32x4 tt = *(const f32x4*)&st[576 + c];
  *(f32x4*)&x2[((size_t)b * 784 + pix) * 576 + c] = acc * s + tt;
}

// ---------- launch ----------
extern "C" void kernel_launch(void* const* d_in, const int* in_sizes, int n_in,
                              void* d_out, int out_size, void* d_ws, size_t ws_size,
                              hipStream_t stream) {
  (void)in_sizes; (void)n_in; (void)out_size; (void)ws_size;
  const float* x      = (const float*)d_in[0];
  const float* ln1g   = (const float*)d_in[1];
  const float* ln1b   = (const float*)d_in[2];
  const float* qkv_w  = (const float*)d_in[3];
  const float* qkv_b  = (const float*)d_in[4];
  const float* biases = (const float*)d_in[5];
  const float* proj_w = (const float*)d_in[6];
  const float* proj_b = (const float*)d_in[7];
  const float* conv_w = (const float*)d_in[8];
  const float* bng    = (const float*)d_in[9];
  const float* bnb    = (const float*)d_in[10];
  const float* bnm    = (const float*)d_in[11];
  const float* bnv    = (const float*)d_in[12];
  const float* ln2g   = (const float*)d_in[13];
  const float* ln2b   = (const float*)d_in[14];
  const float* fc1_w  = (const float*)d_in[15];
  const float* fc1_b  = (const float*)d_in[16];
  const float* fc2_w  = (const float*)d_in[17];
  const float* fc2_b  = (const float*)d_in[18];
  float* out = (float*)d_out;

  const int M = 25088;
  char* ws = (char*)d_ws;
  float* x2 = (float*)ws;
  char* regB = ws + 57802752;
  __hip_bfloat16* qkvb = (__hip_bfloat16*)regB;
  float*          x1   = (float*)regB;
  __hip_bfloat16* hm   = (__hip_bfloat16*)regB;
  char* regC = ws + 173408256;
  __hip_bfloat16* xn1  = (__hip_bfloat16*)regC;
  __hip_bfloat16* obuf = (__hip_bfloat16*)regC;
  __hip_bfloat16* xn2  = (__hip_bfloat16*)regC;
  char* regD = ws + 202309632;
  __hip_bfloat16* qkvT = (__hip_bfloat16*)regD;
  __hip_bfloat16* projT = (__hip_bfloat16*)(regD + 1990656);
  __hip_bfloat16* fc1T  = (__hip_bfloat16*)(regD + 1990656 + 663552);
  __hip_bfloat16* fc2T  = (__hip_bfloat16*)(regD + 1990656 + 663552 + 2654208);
  float* convT = (float*)(ws + 210272256);
  float* convST = convT + 9 * 576;

  // weight prep
  wt_kernel<<<dim3(1728 / 32, 576 / 32), 256, 0, stream>>>(qkv_w, qkvT, 576, 1728);
  wt_kernel<<<dim3(576 / 32, 576 / 32), 256, 0, stream>>>(proj_w, projT, 576, 576);
  wt_kernel<<<dim3(2304 / 32, 576 / 32), 256, 0, stream>>>(fc1_w, fc1T, 576, 2304);
  wt_kernel<<<dim3(576 / 32, 2304 / 32), 256, 0, stream>>>(fc2_w, fc2T, 2304, 576);
  convprep_kernel<<<(576 * 9 + 255) / 256, 256, 0, stream>>>(conv_w, bng, bnb, bnm, bnv, convT, convST);

  // 1. xn1 = LN1(x) bf16
  ln_bf16_kernel<<<M / 4, 256, 0, stream>>>(x, ln1g, ln1b, xn1);
  // 2. qkv = xn1 @ qkv_w + qkv_b (bf16 out); 8-phase, grid 98 x 9
  gemm8<0, __hip_bfloat16><<<98 * 9, 512, 0, stream>>>(xn1, qkvT, qkv_b, nullptr, qkvb, M, 1728, 576);
  // 3. attention
  attn_mfma_kernel<<<512 * 18, 64, 0, stream>>>(qkvb, biases, obuf);
  // 4. x1 = x + (o @ proj_w + proj_b); coarse, grid 98 x 3
  gemm_bt<1, float><<<98 * 3, 512, 0, stream>>>(obuf, projT, proj_b, x, x1, M, 576, 576);
  // 5. x2 = BN(dwconv(x1))
  conv_bn_kernel<<<(32 * 784 * 144 + 255) / 256, 256, 0, stream>>>(x1, convT, convST, x2);
  // 6. xn2 = LN2(x2) bf16
  ln_bf16_kernel<<<M / 4, 256, 0, stream>>>(x2, ln2g, ln2b, xn2);
  // 7. hm = gelu(xn2 @ fc1_w + fc1_b) bf16; 8-phase, grid 98 x 12
  gemm8<2, __hip_bfloat16><<<98 * 12, 512, 0, stream>>>(xn2, fc1T, fc1_b, nullptr, hm, M, 2304, 576);
  // 8. out = x2 + (hm @ fc2_w + fc2_b); coarse, grid 98 x 3
  gemm_bt<1, float><<<98 * 3, 512, 0, stream>>>(hm, fc2T, fc2_b, x2, out, M, 576, 2304);
}